// Round 9
// baseline (125.575 us; speedup 1.0000x reference)
//
#include <hip/hip_runtime.h>
#include <cstdint>

// ModConv: y[b,o,l] = sum_{i,k} bw[b,o,i,k] * x[b,i,l+k-1],
//   bw = conv_w * s[b,i] * demod[b,o],  s = t@mod_w^T + mod_b + 1,
//   demod = rsqrt(sum_{i,k} (conv_w*s)^2 + 1e-8)
// R2-derived structure, scaled: BM=128 x BN=256 tiles (TPB=4 -> half the
// barriers), 8 waves in a 2x4 grid with 64x64 wave-tiles (halves LDS-read
// bytes per FLOP vs 64x32). LDS = A(98304) + XT 256 rows(65536) = 163840
// exactly; no halo rows -> edge taps zeroed in-loop (cndmask) and re-added
// by an in-kernel epilogue that reads the resident LDS A-tile conflict-free
// (4 lanes per o-row, b128 reads, shfl reduce). In-loop barriers are
// lgkmcnt-only (no vmcnt/store drain); stores are NORMAL (R8: NT was -25%).

namespace {
constexpr int NI = 128, NO = 256, NK = 3, NT = 256, NL = 8192;
constexpr int BM = 128, BN = 256, TPB = 4;    // block: 128 o x 1024 l
constexpr int XT_OFF = NK * 128 * 256;        // A: 98304
constexpr int SMEM_BYTES = XT_OFF + 256 * 256;   // 163840 == 160 KiB exactly
constexpr int NPASS = 8;                      // 256 rows / 32 per pass
}

typedef __attribute__((ext_vector_type(8))) short bf16x8;
typedef __attribute__((ext_vector_type(4))) float f32x4;

__device__ __forceinline__ uint32_t f2bf(float f) {
    uint32_t u = __builtin_bit_cast(uint32_t, f);
    return (u + 0x7fffu + ((u >> 16) & 1u)) >> 16;   // RNE
}
__device__ __forceinline__ float bf2f(uint32_t hi) {
    return __builtin_bit_cast(float, hi << 16);
}

// barrier with LDS-only consistency: no vmcnt drain (stores/loads fly on)
__device__ __forceinline__ void lds_barrier() {
    asm volatile("s_waitcnt lgkmcnt(0)" ::: "memory");
    __builtin_amdgcn_s_barrier();
    __builtin_amdgcn_sched_barrier(0);
}

__launch_bounds__(512, 2)
__global__ void modconv(const float* __restrict__ x,
                        const float* __restrict__ tvec,
                        const float* __restrict__ conv_w,
                        const float* __restrict__ mod_w,
                        const float* __restrict__ mod_b,
                        float* __restrict__ out) {
    __shared__ __align__(16) char smem[SMEM_BYTES];
    float* s_sh = reinterpret_cast<float*>(smem + XT_OFF);        // prologue
    float* d_sh = reinterpret_cast<float*>(smem + XT_OFF + 512);  // prologue

    const int tid = threadIdx.x;

    // ---- XCD-paired decode: both o-tiles of one (b,chunk) share bid&7
    const int bid  = blockIdx.x;
    const int slot = bid >> 3;                 // [0,32)
    const int g    = (bid & 7) + 8 * (slot >> 1);   // [0,128): (b,chunk)
    const int m    = slot & 1;
    const int b     = g >> 3;
    const int chunk = g & 7;
    const int o0    = m * BM;
    const int C     = chunk * (TPB * BN);      // 1024-col chunk

    const float* xb = x + (size_t)b * NI * NL;
    float* outb     = out + ((size_t)b * NO + o0) * NL;

    // ---- staged X loads: row r=p*32+lrow <-> col l0+r, 8 i per thread
    float xr[NPASS][8];
    const int lrow = tid & 31, ig = tid >> 5;

    auto issue_loads = [&](int l0s) {
        #pragma unroll
        for (int p = 0; p < NPASS; ++p) {
            const int col = l0s + p * 32 + lrow;      // always in [0,8191]
            const float* px = xb + (size_t)(ig * 8) * NL + col;
            #pragma unroll
            for (int n = 0; n < 8; ++n) xr[p][n] = px[(size_t)n * NL];
        }
    };
    auto write_stage = [&]() {
        #pragma unroll
        for (int p = 0; p < NPASS; ++p) {
            const int r = p * 32 + lrow;
            uint32_t d0 = f2bf(xr[p][0]) | (f2bf(xr[p][1]) << 16);
            uint32_t d1 = f2bf(xr[p][2]) | (f2bf(xr[p][3]) << 16);
            uint32_t d2 = f2bf(xr[p][4]) | (f2bf(xr[p][5]) << 16);
            uint32_t d3 = f2bf(xr[p][6]) | (f2bf(xr[p][7]) << 16);
            *reinterpret_cast<uint4*>(
                smem + XT_OFF + r * 256 + ((ig * 16) ^ ((r & 15) << 4))) =
                make_uint4(d0, d1, d2, d3);
        }
    };

    issue_loads(C);   // tile-0 loads fly under the whole prologue

    // ---- phase 1: s[i] = dot(t[b], mod_w[i]) + mod_b[i] + 1  (4 thr/i)
    {
        const int i = tid >> 2, q = tid & 3;
        const float* tp = tvec + b * NT + q * 64;
        const float* mp = mod_w + (size_t)i * NT + q * 64;
        float acc = 0.f;
        #pragma unroll 8
        for (int j = 0; j < 64; ++j) acc = fmaf(tp[j], mp[j], acc);
        acc += __shfl_xor(acc, 1);
        acc += __shfl_xor(acc, 2);
        if (q == 0) s_sh[i] = acc + mod_b[i] + 1.0f;
    }
    __syncthreads();

    // ---- phase 2: demod[o] (4 thr/o, 128 o)
    {
        const int o_l = tid >> 2, q = tid & 3;
        const float* cw = conv_w + (size_t)(o0 + o_l) * (NI * NK) + q * 32 * NK;
        float sum = 0.f;
        #pragma unroll 4
        for (int ii = 0; ii < 32; ++ii) {
            float s  = s_sh[q * 32 + ii];
            float w0 = cw[ii * 3 + 0], w1 = cw[ii * 3 + 1], w2 = cw[ii * 3 + 2];
            sum = fmaf(s * s, w0 * w0 + w1 * w1 + w2 * w2, sum);
        }
        sum += __shfl_xor(sum, 1);
        sum += __shfl_xor(sum, 2);
        if (q == 0) d_sh[o_l] = rsqrtf(sum + 1e-8f);
    }
    __syncthreads();

    // ---- phase 3: A tile -> LDS bf16: byte(k,o,i)=k*32768+o*256+((i*2)^((o&15)<<4))
    for (int idx = tid; idx < BM * (NI / 2); idx += 512) {
        const int i2 = idx & 63, o = idx >> 6;
        const float* cw = conv_w + ((size_t)(o0 + o) * NI + i2 * 2) * NK;
        const float dm = d_sh[o];
        const float mA = s_sh[i2 * 2] * dm, mB = s_sh[i2 * 2 + 1] * dm;
        const int base = o * 256, sw = (o & 15) << 4;
        #pragma unroll
        for (int k = 0; k < NK; ++k) {
            uint32_t v = f2bf(cw[k] * mA) | (f2bf(cw[k + NK] * mB) << 16);
            *reinterpret_cast<uint32_t*>(
                smem + k * 32768 + base + ((i2 * 4) ^ sw)) = v;
        }
    }
    // A + s/d ordering handled by the loop's first lds_barrier

    const int lane = tid & 63;
    const int wid  = tid >> 6;
    const int wm   = wid >> 2, wn = wid & 3;   // 2x4 waves: 64x64 out each
    const int l16  = lane & 15, lg4 = lane >> 4;
    const bf16x8 zf = {0, 0, 0, 0, 0, 0, 0, 0};

    for (int tile = 0; tile < TPB; ++tile) {
        const int l0 = C + tile * BN;
        lds_barrier();     // prev tile's LDS reads done; prologue writes visible
        write_stage();     // XT <- tile t (compiler waits this tile's vmcnt)
        lds_barrier();     // XT visible
        if (tile + 1 < TPB) issue_loads(l0 + BN);   // t+1 flies under MFMA

        f32x4 acc[4][4];
        const f32x4 zero = {0.f, 0.f, 0.f, 0.f};
        #pragma unroll
        for (int fm = 0; fm < 4; ++fm)
            #pragma unroll
            for (int fn = 0; fn < 4; ++fn) acc[fm][fn] = zero;

        #pragma unroll
        for (int k = 0; k < NK; ++k) {
            #pragma unroll
            for (int kc = 0; kc < 4; ++kc) {
                const int cb = kc * 64 + lg4 * 16;
                bf16x8 af[4], bfr[4];
                #pragma unroll
                for (int fm = 0; fm < 4; ++fm) {
                    const int o = wm * 64 + fm * 16 + l16;
                    af[fm] = *reinterpret_cast<const bf16x8*>(
                        smem + k * 32768 + o * 256 + (cb ^ ((o & 15) << 4)));
                }
                #pragma unroll
                for (int fn = 0; fn < 4; ++fn) {
                    int r = wn * 64 + fn * 16 + l16 + k - 1;
                    r = r < 0 ? 0 : (r > 255 ? 255 : r);
                    bf16x8 f = *reinterpret_cast<const bf16x8*>(
                        smem + XT_OFF + r * 256 + (cb ^ ((r & 15) << 4)));
                    if (k == 0 && fn == 0) f = (wn == 0 && l16 == 0)  ? zf : f;
                    if (k == 2 && fn == 3) f = (wn == 3 && l16 == 15) ? zf : f;
                    bfr[fn] = f;
                }
                #pragma unroll
                for (int fm = 0; fm < 4; ++fm)
                    #pragma unroll
                    for (int fn = 0; fn < 4; ++fn)
                        acc[fm][fn] = __builtin_amdgcn_mfma_f32_16x16x32_bf16(
                            af[fm], bfr[fn], acc[fm][fn], 0, 0, 0);
            }
        }

        // ---- C store (normal f32): row = wm*64+fm*16+lg4*4+j
        #pragma unroll
        for (int fm = 0; fm < 4; ++fm) {
            #pragma unroll
            for (int fn = 0; fn < 4; ++fn) {
                const int og = wm * 64 + fm * 16 + lg4 * 4;
                const int lg = l0 + wn * 64 + fn * 16 + l16;
                #pragma unroll
                for (int j = 0; j < 4; ++j)
                    outb[(size_t)(og + j) * NL + lg] = acc[fm][fn][j];
            }
        }
    }

    // ---- epilogue: re-add zeroed edge taps. unit u = wave: tile t_e, side.
    //      side 0: y[:, l0]      += A0 . x[:, l0-1]
    //      side 1: y[:, l0+255]  += A2 . x[:, l0+256]
    __syncthreads();     // drain all C stores; XT region now free for scratch
    {
        const int u = wid, t_e = u >> 1, side = u & 1;
        const int colY = C + t_e * BN + (side ? 255 : 0);
        const int colX = side ? colY + 1 : colY - 1;
        const bool valid = (colX >= 0) && (colX < NL);
        float* xs = reinterpret_cast<float*>(smem + XT_OFF) + u * 128;

        #pragma unroll
        for (int h = 0; h < 2; ++h) {
            const int i = h * 64 + lane;
            xs[i] = valid ? xb[(size_t)i * NL + colX] : 0.f;
        }
        asm volatile("s_waitcnt lgkmcnt(0)" ::: "memory");
        __builtin_amdgcn_sched_barrier(0);

        const int ktap = side ? 2 : 0;
        const int q = lane & 3;                    // i-quarter (32 i each)
        #pragma unroll 1
        for (int pass = 0; pass < 8; ++pass) {
            const int o = pass * 16 + (lane >> 2);
            float fa = 0.f;
            #pragma unroll
            for (int c4 = 0; c4 < 4; ++c4) {
                const int i0 = q * 32 + c4 * 8;
                const bf16x8 a8 = *reinterpret_cast<const bf16x8*>(
                    smem + ktap * 32768 + o * 256 +
                    ((i0 * 2) ^ ((o & 15) << 4)));
                #pragma unroll
                for (int j = 0; j < 8; ++j)
                    fa = fmaf(bf2f((uint16_t)a8[j]),
                              bf2f(f2bf(xs[i0 + j])), fa);
            }
            fa += __shfl_xor(fa, 1);
            fa += __shfl_xor(fa, 2);
            if (q == 0 && valid) {
                float* p = &outb[(size_t)o * NL + colY];
                *p = *p + fa;
            }
        }
    }
}

extern "C" void kernel_launch(void* const* d_in, const int* in_sizes, int n_in,
                              void* d_out, int out_size, void* d_ws, size_t ws_size,
                              hipStream_t stream) {
    const float* x      = (const float*)d_in[0];
    const float* t      = (const float*)d_in[1];
    const float* conv_w = (const float*)d_in[2];
    const float* mod_w  = (const float*)d_in[3];
    const float* mod_b  = (const float*)d_in[4];

    // 2 o-tiles x 8 chunks x 16 b = 256 blocks = 1 per CU
    modconv<<<dim3(256), dim3(512), 0, stream>>>(x, t, conv_w, mod_w, mod_b,
                                                 (float*)d_out);
}

// Round 10
// 65.606 us; speedup vs baseline: 1.9141x; 1.9141x over previous
//
#include <hip/hip_runtime.h>
#include <cstdint>

// ModConv: y[b,o,l] = sum_{i,k} bw[b,o,i,k] * x[b,i,l+k-1],
//   bw = conv_w * s[b,i] * demod[b,o],  s = t@mod_w^T + mod_b + 1,
//   demod = rsqrt(sum_{i,k} (conv_w*s)^2 + 1e-8)
// EXACTLY the round-2 65us kernel (A-tile in LDS, 130-row X^T, reg-staged
// loads, 512 thr / 8 waves) with ONE change: the two in-loop __syncthreads()
// are lgkmcnt-only barriers, so the per-tile barrier no longer drains
// staging loads + 64KB of C-stores to memory. Stores are PLAIN (round 8
// proved nontemporal stores poison the shared vmcnt queue: +33MB writes,
// slow retirement stalling write_stage's xr waits).

namespace {
constexpr int NB = 16, NI = 128, NO = 256, NK = 3, NT = 256, NL = 8192;
constexpr int BM = 128, BN = 128;
constexpr int TPB = 8;                        // tiles per block (8*128 = 1024 cols)
constexpr int XT_OFF = 3 * 128 * 256;         // A: 3 taps * 128 o * 256B = 98304
constexpr int XT_ROWS = 130;                  // BN + 2 halo
constexpr int SMEM_BYTES = XT_OFF + XT_ROWS * 256;   // 131584 <= 163840
constexpr int NPASS = 5;                      // ceil(130/32) staging passes
}

typedef __attribute__((ext_vector_type(8))) short bf16x8;
typedef __attribute__((ext_vector_type(4))) float f32x4;

__device__ __forceinline__ uint32_t f2bf(float f) {
    uint32_t u = __builtin_bit_cast(uint32_t, f);
    return (u + 0x7fffu + ((u >> 16) & 1u)) >> 16;   // RNE
}

// barrier with LDS-only consistency: do NOT drain global loads/stores
__device__ __forceinline__ void lds_barrier() {
    asm volatile("s_waitcnt lgkmcnt(0)" ::: "memory");
    __builtin_amdgcn_s_barrier();
    __builtin_amdgcn_sched_barrier(0);
}

__launch_bounds__(512, 2)
__global__ void modconv(const float* __restrict__ x,
                        const float* __restrict__ tvec,
                        const float* __restrict__ conv_w,
                        const float* __restrict__ mod_w,
                        const float* __restrict__ mod_b,
                        float* __restrict__ out) {
    __shared__ __align__(16) char smem[SMEM_BYTES];
    // s/d scratch lives in the (not yet used) XT region
    float* s_sh = reinterpret_cast<float*>(smem + XT_OFF);
    float* d_sh = reinterpret_cast<float*>(smem + XT_OFF + 512);

    const int tid = threadIdx.x;

    // ---- XCD-paired block decode: both o-tiles of one (b,chunk) share bid&7
    const int bid  = blockIdx.x;
    const int xcd  = bid & 7;
    const int slot = bid >> 3;          // [0,32)
    const int g    = xcd + 8 * (slot >> 1);   // [0,128): (b,chunk) group
    const int m    = slot & 1;                // o-tile
    const int b     = g >> 3;
    const int chunk = g & 7;
    const int o0    = m * BM;

    const float* xb = x + (size_t)b * NI * NL;
    float* outb     = out + ((size_t)b * NO + o0) * NL;

    // ---- phase 1: s[i] = dot(t[b], mod_w[i]) + mod_b[i] + 1  (4 thr/i)
    {
        const int i = tid >> 2, q = tid & 3;
        const float* tp = tvec + b * NT + q * 64;
        const float* mp = mod_w + i * NT + q * 64;
        float acc = 0.f;
        #pragma unroll 8
        for (int j = 0; j < 64; ++j) acc = fmaf(tp[j], mp[j], acc);
        acc += __shfl_xor(acc, 1);
        acc += __shfl_xor(acc, 2);
        if (q == 0) s_sh[i] = acc + mod_b[i] + 1.0f;
    }
    __syncthreads();

    // ---- phase 2: demod[o] = rsqrt(sum_i s^2 * sum_k w^2 + 1e-8)  (4 thr/o)
    {
        const int o_l = tid >> 2, q = tid & 3;
        const float* cw = conv_w + (size_t)(o0 + o_l) * (NI * NK) + q * 32 * NK;
        float sum = 0.f;
        #pragma unroll 4
        for (int ii = 0; ii < 32; ++ii) {
            float s  = s_sh[q * 32 + ii];
            float w0 = cw[ii * 3 + 0], w1 = cw[ii * 3 + 1], w2 = cw[ii * 3 + 2];
            sum = fmaf(s * s, w0 * w0 + w1 * w1 + w2 * w2, sum);
        }
        sum += __shfl_xor(sum, 1);
        sum += __shfl_xor(sum, 2);
        if (q == 0) d_sh[o_l] = rsqrtf(sum + 1e-8f);
    }
    __syncthreads();

    // ---- staged X loads (tile data held in regs between issue and ds_write)
    float xr[NPASS][8];
    const int lrow = tid & 31;           // row-within-pass (consecutive lanes
    const int ig   = tid >> 5;           //   -> consecutive l: coalesced)

    auto issue_loads = [&](int l0s) {
        #pragma unroll
        for (int p = 0; p < NPASS; ++p) {
            const int r  = p * 32 + lrow;
            const int lg = l0s - 1 + r;
            const bool ok = (r < XT_ROWS) && (lg >= 0) && (lg < NL);
            const float* px = xb + (size_t)(ig * 8) * NL + lg;
            #pragma unroll
            for (int n = 0; n < 8; ++n)
                xr[p][n] = ok ? px[(size_t)n * NL] : 0.0f;
        }
    };
    auto write_stage = [&]() {
        #pragma unroll
        for (int p = 0; p < NPASS; ++p) {
            const int r = p * 32 + lrow;
            if (r < XT_ROWS) {
                uint32_t d0 = f2bf(xr[p][0]) | (f2bf(xr[p][1]) << 16);
                uint32_t d1 = f2bf(xr[p][2]) | (f2bf(xr[p][3]) << 16);
                uint32_t d2 = f2bf(xr[p][4]) | (f2bf(xr[p][5]) << 16);
                uint32_t d3 = f2bf(xr[p][6]) | (f2bf(xr[p][7]) << 16);
                *reinterpret_cast<uint4*>(
                    smem + XT_OFF + r * 256 + ((ig * 16) ^ ((r & 15) << 4))) =
                    make_uint4(d0, d1, d2, d3);
            }
        }
    };

    const int l0_base = chunk * TPB * BN;
    issue_loads(l0_base);   // tile-0 loads fly under the A-fill compute

    // ---- phase 3: A tile (modulated+demodulated weights) -> LDS bf16
    //      byte(k,o,i) = k*32768 + o*256 + ((i*2) ^ ((o&15)<<4)), 2 i per write
    for (int idx = tid; idx < BM * (NI / 2); idx += 512) {
        const int i2 = idx & 63, o = idx >> 6;
        const float* cw = conv_w + ((size_t)(o0 + o) * NI + i2 * 2) * NK;
        const float dm = d_sh[o];
        const float mA = s_sh[i2 * 2] * dm, mB = s_sh[i2 * 2 + 1] * dm;
        const int base = o * 256, sw = (o & 15) << 4;
        #pragma unroll
        for (int k = 0; k < NK; ++k) {
            uint32_t v = f2bf(cw[k] * mA) | (f2bf(cw[k + NK] * mB) << 16);
            *reinterpret_cast<uint32_t*>(
                smem + k * 32768 + base + ((i2 * 4) ^ sw)) = v;
        }
    }
    // A made visible by the first in-loop barrier

    const int lane = tid & 63;
    const int wid  = tid >> 6;
    const int wm   = wid >> 2, wn = wid & 3;   // 2x4 waves: 64x32 out each
    const int l16  = lane & 15, lg4 = lane >> 4;

    for (int tile = 0; tile < TPB; ++tile) {
        const int l0 = l0_base + tile * BN;
        lds_barrier();     // prev tile's LDS reads done -> Xt reusable

        write_stage();     // XT <- tile t (compiler inserts xr vmcnt waits)
        lds_barrier();     // XT visible to all waves

        if (tile + 1 < TPB) issue_loads(l0 + BN);   // t+1 loads fly under MFMA

        // ---- MFMA: 3 taps x 4 K-chunks; wave tile 64(o) x 32(l)
        f32x4 acc[4][2];
        const f32x4 zero = {0.f, 0.f, 0.f, 0.f};
        #pragma unroll
        for (int fm = 0; fm < 4; ++fm)
            #pragma unroll
            for (int fn = 0; fn < 2; ++fn) acc[fm][fn] = zero;

        #pragma unroll
        for (int k = 0; k < NK; ++k) {
            #pragma unroll
            for (int kc = 0; kc < 4; ++kc) {
                const int cb = kc * 64 + lg4 * 16;
                bf16x8 af[4], bfr[2];
                #pragma unroll
                for (int fm = 0; fm < 4; ++fm) {
                    const int o = wm * 64 + fm * 16 + l16;
                    af[fm] = *reinterpret_cast<const bf16x8*>(
                        smem + k * 32768 + o * 256 + (cb ^ ((o & 15) << 4)));
                }
                #pragma unroll
                for (int fn = 0; fn < 2; ++fn) {
                    const int r = wn * 32 + fn * 16 + l16 + k;
                    bfr[fn] = *reinterpret_cast<const bf16x8*>(
                        smem + XT_OFF + r * 256 + (cb ^ ((r & 15) << 4)));
                }
                #pragma unroll
                for (int fm = 0; fm < 4; ++fm)
                    #pragma unroll
                    for (int fn = 0; fn < 2; ++fn)
                        acc[fm][fn] = __builtin_amdgcn_mfma_f32_16x16x32_bf16(
                            af[fm], bfr[fn], acc[fm][fn], 0, 0, 0);
            }
        }

        // ---- write C (f32, PLAIN stores): row = lg4*4 + j within fragment
        #pragma unroll
        for (int fm = 0; fm < 4; ++fm) {
            #pragma unroll
            for (int fn = 0; fn < 2; ++fn) {
                const int og = wm * 64 + fm * 16 + lg4 * 4;
                const int lg = l0 + wn * 32 + fn * 16 + l16;
                #pragma unroll
                for (int j = 0; j < 4; ++j)
                    outb[(size_t)(og + j) * NL + lg] = acc[fm][fn][j];
            }
        }
    }
}

extern "C" void kernel_launch(void* const* d_in, const int* in_sizes, int n_in,
                              void* d_out, int out_size, void* d_ws, size_t ws_size,
                              hipStream_t stream) {
    const float* x      = (const float*)d_in[0];
    const float* t      = (const float*)d_in[1];
    const float* conv_w = (const float*)d_in[2];
    const float* mod_w  = (const float*)d_in[3];
    const float* mod_b  = (const float*)d_in[4];

    modconv<<<dim3(256), dim3(512), 0, stream>>>(x, t, conv_w, mod_w, mod_b,
                                                 (float*)d_out);
}